// Round 1
// baseline (305.008 us; speedup 1.0000x reference)
//
#include <hip/hip_runtime.h>

// Problem constants: B=8, T=256, O=16, D=512, H=8, HD=64
// R = B*T*O = 32768 rows of D=512

typedef __attribute__((ext_vector_type(8))) short bf16x8;
typedef __attribute__((ext_vector_type(4))) float f32x4;

#define MFMA16(a, b, c) __builtin_amdgcn_mfma_f32_16x16x32_bf16((a), (b), (c), 0, 0, 0)

__device__ __forceinline__ unsigned short f2bf(float f) {
  unsigned int u = __builtin_bit_cast(unsigned int, f);
  u += 0x7fffu + ((u >> 16) & 1u);   // RNE
  return (unsigned short)(u >> 16);
}

__device__ __forceinline__ void gload_lds16(const void* g, void* lds) {
  __builtin_amdgcn_global_load_lds((__attribute__((address_space(1))) void*)g,
                                   (__attribute__((address_space(3))) void*)lds,
                                   16, 0, 0);
}

// ---------------- workspace layout (bytes) ----------------
#define WS_XB   0ull            // 32768*512*2 = 33554432  (bf16 X; later reused as att)
#define WS_WT   33554432ull     // 2048*512*2  = 2097152   (rows: Wq^T(512) Wk^T Wv^T Wo^T, each [e][k])
#define WS_Q    35651584ull     // 33554432  (B,O,H,T,HD) bf16
#define WS_K    69206016ull     // 33554432
#define WS_V    102760448ull    // 33554432
#define WS_MASK 136314880ull    // 32768 uchar canonical mask
// total: 136347648 bytes

// ---------------- K0a: X fp32 -> bf16 ----------------
__global__ void k_cvt_x(const float* __restrict__ x, unsigned short* __restrict__ xb) {
  int i = blockIdx.x * 256 + threadIdx.x;   // 16384 blocks -> exactly 4194304 float4
  float4 v = ((const float4*)x)[i];
  ushort4 o;
  o.x = f2bf(v.x); o.y = f2bf(v.y); o.z = f2bf(v.z); o.w = f2bf(v.w);
  ((ushort4*)xb)[i] = o;
}

// ---------------- K0b: weights -> bf16, transposed: Wt[e'][d] = W[d][e] ----------------
__global__ void k_prep_w(const float* __restrict__ Wq, const float* __restrict__ Wk,
                         const float* __restrict__ Wv, const float* __restrict__ Wo,
                         unsigned short* __restrict__ Wt) {
  int ep = blockIdx.x;   // 0..2047
  const float* src; int e;
  if (ep < 512)       { src = Wq; e = ep; }
  else if (ep < 1024) { src = Wk; e = ep - 512; }
  else if (ep < 1536) { src = Wv; e = ep - 1024; }
  else                { src = Wo; e = ep - 1536; }
  for (int d = threadIdx.x; d < 512; d += 256)
    Wt[(size_t)ep * 512 + d] = f2bf(src[(size_t)d * 512 + e]);
}

// ---------------- K0c: canonicalize mask (detect int32 vs byte-packed bool) ----------------
__global__ void k_prep_mask(const void* __restrict__ mraw, unsigned char* __restrict__ mout) {
  const unsigned int* u = (const unsigned int*)mraw;
  int lane = threadIdx.x & 63;
  int packed = __any(u[lane] > 1u);        // bool-packed: bytes {0,1} -> words almost surely >1
  int idx = blockIdx.x * 256 + threadIdx.x; // 128 blocks -> 32768
  unsigned char m;
  if (packed) m = ((const unsigned char*)mraw)[idx] ? 1 : 0;
  else        m = u[idx] ? 1 : 0;
  mout[idx] = m;
}

// ---------------- K1: QKV GEMM ----------------
// grid (512, 3): blockIdx.x = M-tile (64 rows), blockIdx.y = which (0=Q,1=K,2=V)
// block 512 threads = 8 waves; wave w owns cols [w*64, w*64+64) == head w.
// LDS: A-tile [64 rows][64 k] bf16 swizzled (8KB) @0 ; B-tile [512 e][64 k] swizzled (64KB) @8192
__global__ __launch_bounds__(512) void k_qkv(
    const unsigned short* __restrict__ Xb, const unsigned short* __restrict__ Wt,
    const float* __restrict__ bq, const float* __restrict__ bk, const float* __restrict__ bv,
    unsigned short* __restrict__ Qb, unsigned short* __restrict__ Kb, unsigned short* __restrict__ Vb) {
  __shared__ char sm[73728];
  const int tid = threadIdx.x, l = tid & 63, w = tid >> 6;
  const int lane15 = l & 15, quad = l >> 4;
  const int rbase = blockIdx.x * 64, which = blockIdx.y;
  const char* xg = (const char*)Xb;
  const char* wgp = (const char*)(Wt + (size_t)which * 512 * 512);
  const int srow = tid >> 3;            // 0..63
  const int c16 = (tid & 7) * 16;
  const int swz_a = c16 ^ ((srow & 7) << 4);
  char* adst = sm + w * 1024;
  f32x4 acc[4][4] = {};
  for (int ks = 0; ks < 8; ++ks) {
    __syncthreads();
    gload_lds16(xg + (size_t)(rbase + srow) * 1024 + ks * 128 + swz_a, adst);
#pragma unroll
    for (int p = 0; p < 8; ++p) {
      int er = p * 64 + srow;
      gload_lds16(wgp + (size_t)er * 1024 + ks * 128 + (c16 ^ ((er & 7) << 4)),
                  sm + 8192 + p * 8192 + w * 1024);
    }
    __syncthreads();
#pragma unroll
    for (int kc = 0; kc < 2; ++kc) {
      bf16x8 af[4], bfr[4];
#pragma unroll
      for (int mt = 0; mt < 4; ++mt) {
        int row = mt * 16 + lane15;
        int byt = (row * 128 + kc * 64 + quad * 16) ^ ((row & 7) << 4);
        af[mt] = *(const bf16x8*)(sm + byt);
      }
#pragma unroll
      for (int nt = 0; nt < 4; ++nt) {
        int col = w * 64 + nt * 16 + lane15;
        int byt = (col * 128 + kc * 64 + quad * 16) ^ ((col & 7) << 4);
        bfr[nt] = *(const bf16x8*)(sm + 8192 + byt);
      }
#pragma unroll
      for (int mt = 0; mt < 4; ++mt)
#pragma unroll
        for (int nt = 0; nt < 4; ++nt)
          acc[mt][nt] = MFMA16(af[mt], bfr[nt], acc[mt][nt]);
    }
  }
  const float* bias = (which == 0) ? bq : (which == 1) ? bk : bv;
  unsigned short* dst = (which == 0) ? Qb : (which == 1) ? Kb : Vb;
#pragma unroll
  for (int mt = 0; mt < 4; ++mt) {
#pragma unroll
    for (int reg = 0; reg < 4; ++reg) {
      int r = rbase + mt * 16 + quad * 4 + reg;
      int b = r >> 12, t = (r >> 4) & 255, o = r & 15;
      size_t base_bt = (size_t)((b * 16 + o) * 8 + w) * 16384 + (size_t)t * 64;
#pragma unroll
      for (int nt = 0; nt < 4; ++nt) {
        int e = w * 64 + nt * 16 + lane15;
        float v = acc[mt][nt][reg] + bias[e];
        dst[base_bt + nt * 16 + lane15] = f2bf(v);
      }
    }
  }
}

// ---------------- K2: attention per (b,o,h) ----------------
// grid 1024, block 512 = 8 waves; wave w owns queries [w*32, w*32+32).
// 4 key-chunks of 64; online softmax; LDS: K[64][64]swz @0, Vt[64hd][64t]swz @8192,
// P per-wave [32][64]swz @16384+w*4096, mask bias f32[256] @49152.  Total 50176 B.
__global__ __launch_bounds__(512) void k_attn(
    const unsigned short* __restrict__ Qb, const unsigned short* __restrict__ Kb,
    const unsigned short* __restrict__ Vb, const unsigned char* __restrict__ Mc,
    unsigned short* __restrict__ att) {
  __shared__ char sm[50176];
  const int tid = threadIdx.x, l = tid & 63, w = tid >> 6;
  const int lane15 = l & 15, quad = l >> 4;
  const int bid = blockIdx.x;
  const int h = bid & 7, o = (bid >> 3) & 15, b = bid >> 7;
  const size_t head = (size_t)((b * 16 + o) * 8 + h) * 16384;
  const char* kg = (const char*)(Kb + head);
  const char* vg = (const char*)(Vb + head);
  const unsigned short* qh = Qb + head;
  float* maskb = (float*)(sm + 49152);
  if (tid < 256)
    maskb[tid] = Mc[(size_t)(b * 256 + tid) * 16 + o] ? 0.0f : -30000.0f;
  const int q0 = w * 32;
  bf16x8 qf[2][2];
#pragma unroll
  for (int mt = 0; mt < 2; ++mt)
#pragma unroll
    for (int kc = 0; kc < 2; ++kc)
      qf[mt][kc] = *(const bf16x8*)(qh + (size_t)(q0 + mt * 16 + lane15) * 64 + kc * 32 + quad * 8);
  f32x4 pv[2][4] = {};
  float mrun[2][4], srun[2][4];
#pragma unroll
  for (int mt = 0; mt < 2; ++mt)
#pragma unroll
    for (int reg = 0; reg < 4; ++reg) { mrun[mt][reg] = -30000.0f; srun[mt][reg] = 0.0f; }
  const int srow = tid >> 3;
  const int c16 = (tid & 7) * 16;
  char* kdst = sm + w * 1024;
  char* pbase = sm + 16384 + w * 4096;
  for (int c = 0; c < 4; ++c) {
    __syncthreads();
    // stage K chunk (swizzled source -> linear LDS dest)
    gload_lds16(kg + (size_t)(c * 64 + srow) * 128 + (c16 ^ ((srow & 7) << 4)), kdst);
    // stage V chunk transposed into Vt[hd][t'] (swizzled)
    {
      int tl = tid >> 3, hd0 = (tid & 7) * 8;
      bf16x8 vv = *(const bf16x8*)(vg + (size_t)(c * 64 + tl) * 128 + hd0 * 2);
#pragma unroll
      for (int j = 0; j < 8; ++j) {
        int hd = hd0 + j;
        int byt = (hd * 128 + tl * 2) ^ ((hd & 7) << 4);
        *(unsigned short*)(sm + 8192 + byt) = (unsigned short)vv[j];
      }
    }
    __syncthreads();
    // QK^T for this chunk
    f32x4 sacc[2][4] = {};
#pragma unroll
    for (int kc = 0; kc < 2; ++kc) {
      bf16x8 kf[4];
#pragma unroll
      for (int nt = 0; nt < 4; ++nt) {
        int key = nt * 16 + lane15;
        int byt = (key * 128 + kc * 64 + quad * 16) ^ ((key & 7) << 4);
        kf[nt] = *(const bf16x8*)(sm + byt);
      }
#pragma unroll
      for (int mt = 0; mt < 2; ++mt)
#pragma unroll
        for (int nt = 0; nt < 4; ++nt)
          sacc[mt][nt] = MFMA16(qf[mt][kc], kf[nt], sacc[mt][nt]);
    }
    // scale + mask bias
    float bias_v[4];
#pragma unroll
    for (int nt = 0; nt < 4; ++nt) bias_v[nt] = maskb[c * 64 + nt * 16 + lane15];
#pragma unroll
    for (int mt = 0; mt < 2; ++mt) {
#pragma unroll
      for (int nt = 0; nt < 4; ++nt)
#pragma unroll
        for (int reg = 0; reg < 4; ++reg)
          sacc[mt][nt][reg] = sacc[mt][nt][reg] * 0.125f + bias_v[nt];
      // online softmax per (mt,reg) row
#pragma unroll
      for (int reg = 0; reg < 4; ++reg) {
        float mx = fmaxf(fmaxf(sacc[mt][0][reg], sacc[mt][1][reg]),
                         fmaxf(sacc[mt][2][reg], sacc[mt][3][reg]));
#pragma unroll
        for (int d = 1; d < 16; d <<= 1) mx = fmaxf(mx, __shfl_xor(mx, d));
        float mnew = fmaxf(mrun[mt][reg], mx);
        float fac = __expf(mrun[mt][reg] - mnew);
        mrun[mt][reg] = mnew;
        float rs = 0.f;
#pragma unroll
        for (int nt = 0; nt < 4; ++nt) {
          float p = __expf(sacc[mt][nt][reg] - mnew);
          sacc[mt][nt][reg] = p;
          rs += p;
        }
#pragma unroll
        for (int d = 1; d < 16; d <<= 1) rs += __shfl_xor(rs, d);
        srun[mt][reg] = srun[mt][reg] * fac + rs;
#pragma unroll
        for (int nh = 0; nh < 4; ++nh) pv[mt][nh][reg] *= fac;
      }
    }
    // write P (bf16) to wave-private swizzled LDS
#pragma unroll
    for (int mt = 0; mt < 2; ++mt)
#pragma unroll
      for (int nt = 0; nt < 4; ++nt)
#pragma unroll
        for (int reg = 0; reg < 4; ++reg) {
          int qrow = mt * 16 + quad * 4 + reg;
          int byt = (qrow * 128 + (nt * 16 + lane15) * 2) ^ ((qrow & 7) << 4);
          *(unsigned short*)(pbase + byt) = f2bf(sacc[mt][nt][reg]);
        }
    // PV for this chunk (wave-private P; compiler orders ds_write->ds_read)
#pragma unroll
    for (int kc = 0; kc < 2; ++kc) {
      bf16x8 pa[2], vbr[4];
#pragma unroll
      for (int mt = 0; mt < 2; ++mt) {
        int qrow = mt * 16 + lane15;
        int byt = (qrow * 128 + kc * 64 + quad * 16) ^ ((qrow & 7) << 4);
        pa[mt] = *(const bf16x8*)(pbase + byt);
      }
#pragma unroll
      for (int nh = 0; nh < 4; ++nh) {
        int hdr = nh * 16 + lane15;
        int byt = (hdr * 128 + kc * 64 + quad * 16) ^ ((hdr & 7) << 4);
        vbr[nh] = *(const bf16x8*)(sm + 8192 + byt);
      }
#pragma unroll
      for (int mt = 0; mt < 2; ++mt)
#pragma unroll
        for (int nh = 0; nh < 4; ++nh)
          pv[mt][nh] = MFMA16(pa[mt], vbr[nh], pv[mt][nh]);
    }
  }
  // normalize + store att (R,512) bf16
#pragma unroll
  for (int mt = 0; mt < 2; ++mt) {
#pragma unroll
    for (int reg = 0; reg < 4; ++reg) {
      int q = q0 + mt * 16 + quad * 4 + reg;
      float inv = srun[mt][reg] > 0.f ? 1.0f / srun[mt][reg] : 0.f;
      size_t r = (size_t)(b * 256 + q) * 16 + o;
#pragma unroll
      for (int nh = 0; nh < 4; ++nh) {
        int e = h * 64 + nh * 16 + lane15;
        att[r * 512 + e] = f2bf(pv[mt][nh][reg] * inv);
      }
    }
  }
}

// ---------------- K3: O-proj + bias + residual + LayerNorm + mask ----------------
// grid 512 (M-tiles of 64 rows), block 512 = 8 waves (wave w: cols [w*64, w*64+64))
__global__ __launch_bounds__(512) void k_oproj(
    const unsigned short* __restrict__ A, const unsigned short* __restrict__ Wt,
    const float* __restrict__ bo, const float* __restrict__ X,
    const unsigned char* __restrict__ Mc, const float* __restrict__ gamma,
    const float* __restrict__ beta, float* __restrict__ out) {
  __shared__ char sm[73728];
  __shared__ float psum[64][8];
  __shared__ float psumsq[64][8];
  __shared__ float smean[64];
  __shared__ float srstd[64];
  const int tid = threadIdx.x, l = tid & 63, w = tid >> 6;
  const int lane15 = l & 15, quad = l >> 4;
  const int rbase = blockIdx.x * 64;
  const char* ag = (const char*)A;
  const char* wgp = (const char*)(Wt + (size_t)1536 * 512);
  const int srow = tid >> 3;
  const int c16 = (tid & 7) * 16;
  const int swz_a = c16 ^ ((srow & 7) << 4);
  char* adst = sm + w * 1024;
  f32x4 acc[4][4] = {};
  for (int ks = 0; ks < 8; ++ks) {
    __syncthreads();
    gload_lds16(ag + (size_t)(rbase + srow) * 1024 + ks * 128 + swz_a, adst);
#pragma unroll
    for (int p = 0; p < 8; ++p) {
      int er = p * 64 + srow;
      gload_lds16(wgp + (size_t)er * 1024 + ks * 128 + (c16 ^ ((er & 7) << 4)),
                  sm + 8192 + p * 8192 + w * 1024);
    }
    __syncthreads();
#pragma unroll
    for (int kc = 0; kc < 2; ++kc) {
      bf16x8 af[4], bfr[4];
#pragma unroll
      for (int mt = 0; mt < 4; ++mt) {
        int row = mt * 16 + lane15;
        int byt = (row * 128 + kc * 64 + quad * 16) ^ ((row & 7) << 4);
        af[mt] = *(const bf16x8*)(sm + byt);
      }
#pragma unroll
      for (int nt = 0; nt < 4; ++nt) {
        int col = w * 64 + nt * 16 + lane15;
        int byt = (col * 128 + kc * 64 + quad * 16) ^ ((col & 7) << 4);
        bfr[nt] = *(const bf16x8*)(sm + 8192 + byt);
      }
#pragma unroll
      for (int mt = 0; mt < 4; ++mt)
#pragma unroll
        for (int nt = 0; nt < 4; ++nt)
          acc[mt][nt] = MFMA16(af[mt], bfr[nt], acc[mt][nt]);
    }
  }
  // epilogue: v = acc + bo + x ; row stats across 8 waves via LDS
#pragma unroll
  for (int mt = 0; mt < 4; ++mt) {
#pragma unroll
    for (int reg = 0; reg < 4; ++reg) {
      int rl = mt * 16 + quad * 4 + reg;
      int r = rbase + rl;
      float s1 = 0.f, s2 = 0.f;
#pragma unroll
      for (int nt = 0; nt < 4; ++nt) {
        int col = w * 64 + nt * 16 + lane15;
        float v = acc[mt][nt][reg] + bo[col] + X[(size_t)r * 512 + col];
        acc[mt][nt][reg] = v;
        s1 += v; s2 += v * v;
      }
#pragma unroll
      for (int d = 1; d < 16; d <<= 1) { s1 += __shfl_xor(s1, d); s2 += __shfl_xor(s2, d); }
      if (lane15 == 0) { psum[rl][w] = s1; psumsq[rl][w] = s2; }
    }
  }
  __syncthreads();
  if (tid < 64) {
    float a = 0.f, q = 0.f;
#pragma unroll
    for (int j = 0; j < 8; ++j) { a += psum[tid][j]; q += psumsq[tid][j]; }
    float mu = a * (1.f / 512.f);
    float var = q * (1.f / 512.f) - mu * mu;
    smean[tid] = mu;
    srstd[tid] = rsqrtf(fmaxf(var, 0.f) + 1e-5f);
  }
  __syncthreads();
#pragma unroll
  for (int mt = 0; mt < 4; ++mt) {
#pragma unroll
    for (int reg = 0; reg < 4; ++reg) {
      int rl = mt * 16 + quad * 4 + reg;
      int r = rbase + rl;
      float mu = smean[rl], rs = srstd[rl];
      float mkf = Mc[r] ? 1.f : 0.f;
#pragma unroll
      for (int nt = 0; nt < 4; ++nt) {
        int col = w * 64 + nt * 16 + lane15;
        float y = (acc[mt][nt][reg] - mu) * rs * gamma[col] + beta[col];
        out[(size_t)r * 512 + col] = y * mkf;
      }
    }
  }
}

// ---------------- host ----------------
extern "C" void kernel_launch(void* const* d_in, const int* in_sizes, int n_in,
                              void* d_out, int out_size, void* d_ws, size_t ws_size,
                              hipStream_t stream) {
  const float* X     = (const float*)d_in[0];
  const void*  Mraw  = d_in[1];
  const float* Wq    = (const float*)d_in[2];
  const float* bq    = (const float*)d_in[3];
  const float* Wk    = (const float*)d_in[4];
  const float* bk    = (const float*)d_in[5];
  const float* Wv    = (const float*)d_in[6];
  const float* bv    = (const float*)d_in[7];
  const float* Wo    = (const float*)d_in[8];
  const float* bo    = (const float*)d_in[9];
  const float* gamma = (const float*)d_in[10];
  const float* beta  = (const float*)d_in[11];

  char* ws = (char*)d_ws;
  unsigned short* Xb  = (unsigned short*)(ws + WS_XB);
  unsigned short* Wt  = (unsigned short*)(ws + WS_WT);
  unsigned short* Qb  = (unsigned short*)(ws + WS_Q);
  unsigned short* Kb  = (unsigned short*)(ws + WS_K);
  unsigned short* Vb  = (unsigned short*)(ws + WS_V);
  unsigned char*  Mc  = (unsigned char*)(ws + WS_MASK);
  unsigned short* att = Xb;  // alias: Xb dead after k_qkv

  hipLaunchKernelGGL(k_cvt_x,    dim3(16384),   dim3(256), 0, stream, X, Xb);
  hipLaunchKernelGGL(k_prep_w,   dim3(2048),    dim3(256), 0, stream, Wq, Wk, Wv, Wo, Wt);
  hipLaunchKernelGGL(k_prep_mask,dim3(128),     dim3(256), 0, stream, Mraw, Mc);
  hipLaunchKernelGGL(k_qkv,      dim3(512, 3),  dim3(512), 0, stream, Xb, Wt, bq, bk, bv, Qb, Kb, Vb);
  hipLaunchKernelGGL(k_attn,     dim3(1024),    dim3(512), 0, stream, Qb, Kb, Vb, Mc, att);
  hipLaunchKernelGGL(k_oproj,    dim3(512),     dim3(512), 0, stream, att, Wt, bo, X, Mc, gamma, beta,
                     (float*)d_out);
}

// Round 3
// 295.105 us; speedup vs baseline: 1.0336x; 1.0336x over previous
//
#include <hip/hip_runtime.h>

// Problem constants: B=8, T=256, O=16, D=512, H=8, HD=64
// R = B*T*O = 32768 rows of D=512

typedef __attribute__((ext_vector_type(8))) short bf16x8;
typedef __attribute__((ext_vector_type(4))) float f32x4;

#define MFMA16(a, b, c) __builtin_amdgcn_mfma_f32_16x16x32_bf16((a), (b), (c), 0, 0, 0)

__device__ __forceinline__ unsigned short f2bf(float f) {
  unsigned int u = __builtin_bit_cast(unsigned int, f);
  u += 0x7fffu + ((u >> 16) & 1u);   // RNE
  return (unsigned short)(u >> 16);
}

__device__ __forceinline__ void gload_lds16(const void* g, void* lds) {
  __builtin_amdgcn_global_load_lds((__attribute__((address_space(1))) void*)g,
                                   (__attribute__((address_space(3))) void*)lds,
                                   16, 0, 0);
}

// ---------------- workspace layout (bytes) ----------------
#define WS_XB   0ull            // 32768*512*2 = 33554432  (bf16 X; later reused as att)
#define WS_WT   33554432ull     // 2048*512*2  = 2097152   (rows: Wq^T(512) Wk^T Wv^T Wo^T, each [e][k])
#define WS_Q    35651584ull     // 33554432  (B,O,H,T,HD) bf16
#define WS_K    69206016ull     // 33554432
#define WS_V    102760448ull    // 33554432
#define WS_MASK 136314880ull    // 32768 uchar canonical mask
// total: 136347648 bytes

// ---------------- K0a: X fp32 -> bf16 ----------------
__global__ void k_cvt_x(const float* __restrict__ x, unsigned short* __restrict__ xb) {
  int i = blockIdx.x * 256 + threadIdx.x;   // 16384 blocks -> exactly 4194304 float4
  float4 v = ((const float4*)x)[i];
  ushort4 o;
  o.x = f2bf(v.x); o.y = f2bf(v.y); o.z = f2bf(v.z); o.w = f2bf(v.w);
  ((ushort4*)xb)[i] = o;
}

// ---------------- K0b: weights -> bf16, transposed: Wt[e'][d] = W[d][e] ----------------
__global__ void k_prep_w(const float* __restrict__ Wq, const float* __restrict__ Wk,
                         const float* __restrict__ Wv, const float* __restrict__ Wo,
                         unsigned short* __restrict__ Wt) {
  int ep = blockIdx.x;   // 0..2047
  const float* src; int e;
  if (ep < 512)       { src = Wq; e = ep; }
  else if (ep < 1024) { src = Wk; e = ep - 512; }
  else if (ep < 1536) { src = Wv; e = ep - 1024; }
  else                { src = Wo; e = ep - 1536; }
  for (int d = threadIdx.x; d < 512; d += 256)
    Wt[(size_t)ep * 512 + d] = f2bf(src[(size_t)d * 512 + e]);
}

// ---------------- K0c: canonicalize mask (detect int32 vs byte-packed bool) ----------------
__global__ void k_prep_mask(const void* __restrict__ mraw, unsigned char* __restrict__ mout) {
  const unsigned int* u = (const unsigned int*)mraw;
  int lane = threadIdx.x & 63;
  int packed = __any(u[lane] > 1u);        // bool-packed: bytes {0,1} -> words almost surely >1
  int idx = blockIdx.x * 256 + threadIdx.x; // 128 blocks -> 32768
  unsigned char m;
  if (packed) m = ((const unsigned char*)mraw)[idx] ? 1 : 0;
  else        m = u[idx] ? 1 : 0;
  mout[idx] = m;
}

// ---------------- K1: QKV GEMM ----------------
// grid (512, 3): blockIdx.x = M-tile (64 rows), blockIdx.y = which (0=Q,1=K,2=V)
// block 512 threads = 8 waves; wave w owns cols [w*64, w*64+64) == head w.
// LDS: A-tile [64 rows][64 k] bf16 swizzled (8KB) @0 ; B-tile [512 e][64 k] swizzled (64KB) @8192
__global__ __launch_bounds__(512) void k_qkv(
    const unsigned short* __restrict__ Xb, const unsigned short* __restrict__ Wt,
    const float* __restrict__ bq, const float* __restrict__ bk, const float* __restrict__ bv,
    unsigned short* __restrict__ Qb, unsigned short* __restrict__ Kb, unsigned short* __restrict__ Vb) {
  __shared__ char sm[73728];
  const int tid = threadIdx.x, l = tid & 63, w = tid >> 6;
  const int lane15 = l & 15, quad = l >> 4;
  const int rbase = blockIdx.x * 64, which = blockIdx.y;
  const char* xg = (const char*)Xb;
  const char* wgp = (const char*)(Wt + (size_t)which * 512 * 512);
  const int srow = tid >> 3;            // 0..63
  const int c16 = (tid & 7) * 16;
  const int swz_a = c16 ^ ((srow & 7) << 4);
  char* adst = sm + w * 1024;
  f32x4 acc[4][4] = {};
  for (int ks = 0; ks < 8; ++ks) {
    __syncthreads();
    gload_lds16(xg + (size_t)(rbase + srow) * 1024 + ks * 128 + swz_a, adst);
#pragma unroll
    for (int p = 0; p < 8; ++p) {
      int er = p * 64 + srow;
      gload_lds16(wgp + (size_t)er * 1024 + ks * 128 + (c16 ^ ((er & 7) << 4)),
                  sm + 8192 + p * 8192 + w * 1024);
    }
    __syncthreads();
#pragma unroll
    for (int kc = 0; kc < 2; ++kc) {
      bf16x8 af[4], bfr[4];
#pragma unroll
      for (int mt = 0; mt < 4; ++mt) {
        int row = mt * 16 + lane15;
        int byt = (row * 128 + kc * 64 + quad * 16) ^ ((row & 7) << 4);
        af[mt] = *(const bf16x8*)(sm + byt);
      }
#pragma unroll
      for (int nt = 0; nt < 4; ++nt) {
        int col = w * 64 + nt * 16 + lane15;
        int byt = (col * 128 + kc * 64 + quad * 16) ^ ((col & 7) << 4);
        bfr[nt] = *(const bf16x8*)(sm + 8192 + byt);
      }
#pragma unroll
      for (int mt = 0; mt < 4; ++mt)
#pragma unroll
        for (int nt = 0; nt < 4; ++nt)
          acc[mt][nt] = MFMA16(af[mt], bfr[nt], acc[mt][nt]);
    }
  }
  const float* bias = (which == 0) ? bq : (which == 1) ? bk : bv;
  unsigned short* dst = (which == 0) ? Qb : (which == 1) ? Kb : Vb;
#pragma unroll
  for (int mt = 0; mt < 4; ++mt) {
#pragma unroll
    for (int reg = 0; reg < 4; ++reg) {
      int r = rbase + mt * 16 + quad * 4 + reg;
      int b = r >> 12, t = (r >> 4) & 255, o = r & 15;
      size_t base_bt = (size_t)((b * 16 + o) * 8 + w) * 16384 + (size_t)t * 64;
#pragma unroll
      for (int nt = 0; nt < 4; ++nt) {
        int e = w * 64 + nt * 16 + lane15;
        float v = acc[mt][nt][reg] + bias[e];
        dst[base_bt + nt * 16 + lane15] = f2bf(v);
      }
    }
  }
}

// ---------------- K2: attention per (b,o,h) — single-pass full-S ----------------
// grid 1024, block 512 = 8 waves; wave w owns queries [w*32, w*32+32).
// All 256 keys staged once; S[32][256] held in registers (sacc[2][16] f32x4/thread).
// LDS: K[256][64] swz @0 (32KB), Vt[64hd][256t] swz @32768 (32KB),
//      P per-wave [32][64] swz @65536+w*4096 (32KB), maskb f32[256] @98304. 99328 B total.
// ONE __syncthreads; softmax in log2 domain (scale 0.125*log2e, mask bias -43280).
__global__ __launch_bounds__(512, 2) void k_attn(
    const unsigned short* __restrict__ Qb, const unsigned short* __restrict__ Kb,
    const unsigned short* __restrict__ Vb, const unsigned char* __restrict__ Mc,
    unsigned short* __restrict__ att) {
  __shared__ char sm[99328];
  const int tid = threadIdx.x, l = tid & 63, w = tid >> 6;
  const int lane15 = l & 15, quad = l >> 4;
  const int bid = blockIdx.x;
  const int h = bid & 7, o = (bid >> 3) & 15, b = bid >> 7;
  const size_t head = (size_t)((b * 16 + o) * 8 + h) * 16384;
  const unsigned short* qh = Qb + head;
  const char* kg = (const char*)(Kb + head);
  const unsigned short* vh = Vb + head;

  // --- stage all K: 4 x (512 threads x 16B) gload_lds, swizzled source -> linear dest ---
  {
    const int srow = tid >> 3;            // 0..63
    const int c16 = (tid & 7) * 16;
    char* kdst = sm + w * 1024;
#pragma unroll
    for (int i = 0; i < 4; ++i) {
      int t = i * 64 + srow;
      gload_lds16(kg + (size_t)t * 128 + (c16 ^ ((t & 7) << 4)), kdst + i * 8192);
    }
  }
  // --- Q fragments (global, independent of LDS) ---
  const int q0 = w * 32;
  bf16x8 qf[2][2];
#pragma unroll
  for (int mt = 0; mt < 2; ++mt)
#pragma unroll
    for (int kc = 0; kc < 2; ++kc)
      qf[mt][kc] = *(const bf16x8*)(qh + (size_t)(q0 + mt * 16 + lane15) * 64 + kc * 32 + quad * 8);
  // --- V column-fragment gather (each load instr: 64 lanes x 2B consecutive = coalesced) ---
  unsigned short vreg[32];
  {
    const int hd = tid & 63, tq = tid >> 6;
#pragma unroll
    for (int i = 0; i < 4; ++i)
#pragma unroll
      for (int j = 0; j < 8; ++j)
        vreg[i * 8 + j] = vh[(size_t)(tq * 32 + i * 8 + j) * 64 + hd];
  }
  // --- mask bias (log2 domain) ---
  float* maskb = (float*)(sm + 98304);
  if (tid < 256)
    maskb[tid] = Mc[(size_t)(b * 256 + tid) * 16 + o] ? 0.0f : -43280.0f;
  // --- Vt pack + conflict-free b128 writes: Vt[hd][t], row 512B, swz (hd&7)<<4 ---
  {
    const int hd = tid & 63, tq = tid >> 6;
    const int rowb = 32768 + hd * 512;
    const int swz = (hd & 7) << 4;
#pragma unroll
    for (int i = 0; i < 4; ++i) {
      bf16x8 pk;
#pragma unroll
      for (int j = 0; j < 8; ++j) pk[j] = (short)vreg[i * 8 + j];
      int t0 = tq * 32 + i * 8;
      *(bf16x8*)(sm + rowb + ((t0 * 2) ^ swz)) = pk;
    }
  }
  __syncthreads();   // the only block-wide barrier

  // --- QK^T: all 256 keys -> sacc[2][16] (S rows q=mt*16+quad*4+reg, cols key=g*16+lane15)
  f32x4 sacc[2][16] = {};
#pragma unroll
  for (int c = 0; c < 4; ++c) {
#pragma unroll
    for (int kc = 0; kc < 2; ++kc) {
      bf16x8 kf[4];
#pragma unroll
      for (int nt = 0; nt < 4; ++nt) {
        int t = c * 64 + nt * 16 + lane15;
        int byt = t * 128 + ((kc * 64 + quad * 16) ^ ((t & 7) << 4));
        kf[nt] = *(const bf16x8*)(sm + byt);
      }
#pragma unroll
      for (int mt = 0; mt < 2; ++mt)
#pragma unroll
        for (int nt = 0; nt < 4; ++nt)
          sacc[mt][c * 4 + nt] = MFMA16(qf[mt][kc], kf[nt], sacc[mt][c * 4 + nt]);
    }
  }

  // --- single-pass softmax (log2 domain): per (mt,reg) row, 16 in-thread + 16-lane shfl ---
  float biasv[16];
#pragma unroll
  for (int g = 0; g < 16; ++g) biasv[g] = maskb[g * 16 + lane15];
  float inv[2][4];
#pragma unroll
  for (int mt = 0; mt < 2; ++mt) {
#pragma unroll
    for (int reg = 0; reg < 4; ++reg) {
      float v[16];
#pragma unroll
      for (int g = 0; g < 16; ++g)
        v[g] = sacc[mt][g][reg] * 0.18033688f + biasv[g];   // 0.125*log2(e)
      float m = v[0];
#pragma unroll
      for (int g = 1; g < 16; ++g) m = fmaxf(m, v[g]);
#pragma unroll
      for (int d = 1; d < 16; d <<= 1) m = fmaxf(m, __shfl_xor(m, d));
      float rs = 0.f;
#pragma unroll
      for (int g = 0; g < 16; ++g) {
        float p = __builtin_amdgcn_exp2f(v[g] - m);          // masked keys -> exact 0
        sacc[mt][g][reg] = p;
        rs += p;
      }
#pragma unroll
      for (int d = 1; d < 16; d <<= 1) rs += __shfl_xor(rs, d);
      inv[mt][reg] = 1.0f / rs;                               // rs >= 1 always (max elem -> 1)
    }
  }

  // --- PV: per 64-key chunk, write P (wave-private) then 16 MFMAs ---
  char* pb = sm + 65536 + w * 4096;
  f32x4 pv[2][4] = {};
#pragma unroll
  for (int c = 0; c < 4; ++c) {
#pragma unroll
    for (int mt = 0; mt < 2; ++mt)
#pragma unroll
      for (int nt = 0; nt < 4; ++nt)
#pragma unroll
        for (int reg = 0; reg < 4; ++reg) {
          int qrow = mt * 16 + quad * 4 + reg;
          int byt = (qrow * 128 + (nt * 16 + lane15) * 2) ^ ((qrow & 7) << 4);
          *(unsigned short*)(pb + byt) = f2bf(sacc[mt][c * 4 + nt][reg]);
        }
#pragma unroll
    for (int kc = 0; kc < 2; ++kc) {
      bf16x8 pa[2], vbr[4];
#pragma unroll
      for (int mt = 0; mt < 2; ++mt) {
        int qrow = mt * 16 + lane15;
        int byt = (qrow * 128 + kc * 64 + quad * 16) ^ ((qrow & 7) << 4);
        pa[mt] = *(const bf16x8*)(pb + byt);
      }
#pragma unroll
      for (int nh = 0; nh < 4; ++nh) {
        int hd = nh * 16 + lane15;
        int byt = hd * 512 + ((c * 128 + kc * 64 + quad * 16) ^ ((hd & 7) << 4));
        vbr[nh] = *(const bf16x8*)(sm + 32768 + byt);
      }
#pragma unroll
      for (int mt = 0; mt < 2; ++mt)
#pragma unroll
        for (int nh = 0; nh < 4; ++nh)
          pv[mt][nh] = MFMA16(pa[mt], vbr[nh], pv[mt][nh]);
    }
  }

  // --- normalize + store att (R,512) bf16 ---
#pragma unroll
  for (int mt = 0; mt < 2; ++mt) {
#pragma unroll
    for (int reg = 0; reg < 4; ++reg) {
      int q = q0 + mt * 16 + quad * 4 + reg;
      size_t r = (size_t)(b * 256 + q) * 16 + o;
      float iv = inv[mt][reg];
#pragma unroll
      for (int nh = 0; nh < 4; ++nh)
        att[r * 512 + h * 64 + nh * 16 + lane15] = f2bf(pv[mt][nh][reg] * iv);
    }
  }
}

// ---------------- K3: O-proj + bias + residual + LayerNorm + mask ----------------
// grid 512 (M-tiles of 64 rows), block 512 = 8 waves (wave w: cols [w*64, w*64+64))
__global__ __launch_bounds__(512) void k_oproj(
    const unsigned short* __restrict__ A, const unsigned short* __restrict__ Wt,
    const float* __restrict__ bo, const float* __restrict__ X,
    const unsigned char* __restrict__ Mc, const float* __restrict__ gamma,
    const float* __restrict__ beta, float* __restrict__ out) {
  __shared__ char sm[73728];
  __shared__ float psum[64][8];
  __shared__ float psumsq[64][8];
  __shared__ float smean[64];
  __shared__ float srstd[64];
  const int tid = threadIdx.x, l = tid & 63, w = tid >> 6;
  const int lane15 = l & 15, quad = l >> 4;
  const int rbase = blockIdx.x * 64;
  const char* ag = (const char*)A;
  const char* wgp = (const char*)(Wt + (size_t)1536 * 512);
  const int srow = tid >> 3;
  const int c16 = (tid & 7) * 16;
  const int swz_a = c16 ^ ((srow & 7) << 4);
  char* adst = sm + w * 1024;
  f32x4 acc[4][4] = {};
  for (int ks = 0; ks < 8; ++ks) {
    __syncthreads();
    gload_lds16(ag + (size_t)(rbase + srow) * 1024 + ks * 128 + swz_a, adst);
#pragma unroll
    for (int p = 0; p < 8; ++p) {
      int er = p * 64 + srow;
      gload_lds16(wgp + (size_t)er * 1024 + ks * 128 + (c16 ^ ((er & 7) << 4)),
                  sm + 8192 + p * 8192 + w * 1024);
    }
    __syncthreads();
#pragma unroll
    for (int kc = 0; kc < 2; ++kc) {
      bf16x8 af[4], bfr[4];
#pragma unroll
      for (int mt = 0; mt < 4; ++mt) {
        int row = mt * 16 + lane15;
        int byt = (row * 128 + kc * 64 + quad * 16) ^ ((row & 7) << 4);
        af[mt] = *(const bf16x8*)(sm + byt);
      }
#pragma unroll
      for (int nt = 0; nt < 4; ++nt) {
        int col = w * 64 + nt * 16 + lane15;
        int byt = (col * 128 + kc * 64 + quad * 16) ^ ((col & 7) << 4);
        bfr[nt] = *(const bf16x8*)(sm + 8192 + byt);
      }
#pragma unroll
      for (int mt = 0; mt < 4; ++mt)
#pragma unroll
        for (int nt = 0; nt < 4; ++nt)
          acc[mt][nt] = MFMA16(af[mt], bfr[nt], acc[mt][nt]);
    }
  }
  // epilogue: v = acc + bo + x ; row stats across 8 waves via LDS
#pragma unroll
  for (int mt = 0; mt < 4; ++mt) {
#pragma unroll
    for (int reg = 0; reg < 4; ++reg) {
      int rl = mt * 16 + quad * 4 + reg;
      int r = rbase + rl;
      float s1 = 0.f, s2 = 0.f;
#pragma unroll
      for (int nt = 0; nt < 4; ++nt) {
        int col = w * 64 + nt * 16 + lane15;
        float v = acc[mt][nt][reg] + bo[col] + X[(size_t)r * 512 + col];
        acc[mt][nt][reg] = v;
        s1 += v; s2 += v * v;
      }
#pragma unroll
      for (int d = 1; d < 16; d <<= 1) { s1 += __shfl_xor(s1, d); s2 += __shfl_xor(s2, d); }
      if (lane15 == 0) { psum[rl][w] = s1; psumsq[rl][w] = s2; }
    }
  }
  __syncthreads();
  if (tid < 64) {
    float a = 0.f, q = 0.f;
#pragma unroll
    for (int j = 0; j < 8; ++j) { a += psum[tid][j]; q += psumsq[tid][j]; }
    float mu = a * (1.f / 512.f);
    float var = q * (1.f / 512.f) - mu * mu;
    smean[tid] = mu;
    srstd[tid] = rsqrtf(fmaxf(var, 0.f) + 1e-5f);
  }
  __syncthreads();
#pragma unroll
  for (int mt = 0; mt < 4; ++mt) {
#pragma unroll
    for (int reg = 0; reg < 4; ++reg) {
      int rl = mt * 16 + quad * 4 + reg;
      int r = rbase + rl;
      float mu = smean[rl], rs = srstd[rl];
      float mkf = Mc[r] ? 1.f : 0.f;
#pragma unroll
      for (int nt = 0; nt < 4; ++nt) {
        int col = w * 64 + nt * 16 + lane15;
        float y = (acc[mt][nt][reg] - mu) * rs * gamma[col] + beta[col];
        out[(size_t)r * 512 + col] = y * mkf;
      }
    }
  }
}

// ---------------- host ----------------
extern "C" void kernel_launch(void* const* d_in, const int* in_sizes, int n_in,
                              void* d_out, int out_size, void* d_ws, size_t ws_size,
                              hipStream_t stream) {
  const float* X     = (const float*)d_in[0];
  const void*  Mraw  = d_in[1];
  const float* Wq    = (const float*)d_in[2];
  const float* bq    = (const float*)d_in[3];
  const float* Wk    = (const float*)d_in[4];
  const float* bk    = (const float*)d_in[5];
  const float* Wv    = (const float*)d_in[6];
  const float* bv    = (const float*)d_in[7];
  const float* Wo    = (const float*)d_in[8];
  const float* bo    = (const float*)d_in[9];
  const float* gamma = (const float*)d_in[10];
  const float* beta  = (const float*)d_in[11];

  char* ws = (char*)d_ws;
  unsigned short* Xb  = (unsigned short*)(ws + WS_XB);
  unsigned short* Wt  = (unsigned short*)(ws + WS_WT);
  unsigned short* Qb  = (unsigned short*)(ws + WS_Q);
  unsigned short* Kb  = (unsigned short*)(ws + WS_K);
  unsigned short* Vb  = (unsigned short*)(ws + WS_V);
  unsigned char*  Mc  = (unsigned char*)(ws + WS_MASK);
  unsigned short* att = Xb;  // alias: Xb dead after k_qkv

  hipLaunchKernelGGL(k_cvt_x,    dim3(16384),   dim3(256), 0, stream, X, Xb);
  hipLaunchKernelGGL(k_prep_w,   dim3(2048),    dim3(256), 0, stream, Wq, Wk, Wv, Wo, Wt);
  hipLaunchKernelGGL(k_prep_mask,dim3(128),     dim3(256), 0, stream, Mraw, Mc);
  hipLaunchKernelGGL(k_qkv,      dim3(512, 3),  dim3(512), 0, stream, Xb, Wt, bq, bk, bv, Qb, Kb, Vb);
  hipLaunchKernelGGL(k_attn,     dim3(1024),    dim3(512), 0, stream, Qb, Kb, Vb, Mc, att);
  hipLaunchKernelGGL(k_oproj,    dim3(512),     dim3(512), 0, stream, att, Wt, bo, X, Mc, gamma, beta,
                     (float*)d_out);
}